// Round 1
// baseline (205.549 us; speedup 1.0000x reference)
//
#include <hip/hip_runtime.h>
#include <math.h>

// Problem constants
#define DM   512
#define NH   8
#define HD   64          // head dim
#define B_   2
#define L_   1024
#define M_   (B_ * L_)   // 2048 rows

// ---------------- fp32 tiled GEMM: C = A @ W^T + bias ----------------
// A: (M, K) row-major, W: (N, K) row-major, C: (M, N).
// Tile: 64x64, BK=32, 256 threads, 4x4 micro-tile per thread.
#define GM 64
#define GN 64
#define GK 32

__device__ __forceinline__ void gemm_tile(const float* __restrict__ A,
                                          const float* __restrict__ W,
                                          const float* __restrict__ bias,
                                          float* __restrict__ C,
                                          int Kd, int N) {
    __shared__ float As[GM][GK + 1];
    __shared__ float Ws[GN][GK + 1];
    const int tid = threadIdx.x;
    const int tx = tid & 15, ty = tid >> 4;
    const int m0 = blockIdx.y * GM, n0 = blockIdx.x * GN;

    float acc[4][4] = {{0.f}};

    for (int k0 = 0; k0 < Kd; k0 += GK) {
        // 64x32 = 2048 floats per tile = 512 float4 -> 2 per thread
#pragma unroll
        for (int t = 0; t < 2; ++t) {
            int idx = tid + t * 256;      // 0..511
            int r = idx >> 3;             // row 0..63
            int c = (idx & 7) << 2;       // col 0..28 step 4
            float4 av = *(const float4*)(A + (size_t)(m0 + r) * Kd + k0 + c);
            As[r][c + 0] = av.x; As[r][c + 1] = av.y;
            As[r][c + 2] = av.z; As[r][c + 3] = av.w;
            float4 wv = *(const float4*)(W + (size_t)(n0 + r) * Kd + k0 + c);
            Ws[r][c + 0] = wv.x; Ws[r][c + 1] = wv.y;
            Ws[r][c + 2] = wv.z; Ws[r][c + 3] = wv.w;
        }
        __syncthreads();
#pragma unroll
        for (int kk = 0; kk < GK; ++kk) {
            float a[4], w[4];
#pragma unroll
            for (int i = 0; i < 4; ++i) a[i] = As[ty * 4 + i][kk];
#pragma unroll
            for (int j = 0; j < 4; ++j) w[j] = Ws[tx * 4 + j][kk];
#pragma unroll
            for (int i = 0; i < 4; ++i)
#pragma unroll
                for (int j = 0; j < 4; ++j) acc[i][j] += a[i] * w[j];
        }
        __syncthreads();
    }

    const int n = n0 + tx * 4;
    float b0 = bias[n + 0], b1 = bias[n + 1], b2 = bias[n + 2], b3 = bias[n + 3];
#pragma unroll
    for (int i = 0; i < 4; ++i) {
        int m = m0 + ty * 4 + i;
        float4 o;
        o.x = acc[i][0] + b0; o.y = acc[i][1] + b1;
        o.z = acc[i][2] + b2; o.w = acc[i][3] + b3;
        *(float4*)(C + (size_t)m * N + n) = o;
    }
}

// Fused Q,K,V projection: grid.z selects which weight/out
__global__ __launch_bounds__(256) void gemm_qkv_kernel(
    const float* __restrict__ x,
    const float* __restrict__ Wq, const float* __restrict__ bq,
    const float* __restrict__ Wk, const float* __restrict__ bk,
    const float* __restrict__ Wv, const float* __restrict__ bv,
    float* __restrict__ Q, float* __restrict__ K, float* __restrict__ V) {
    const float* W; const float* b; float* C;
    if (blockIdx.z == 0)      { W = Wq; b = bq; C = Q; }
    else if (blockIdx.z == 1) { W = Wk; b = bk; C = K; }
    else                      { W = Wv; b = bv; C = V; }
    gemm_tile(x, W, b, C, DM, DM);
}

__global__ __launch_bounds__(256) void gemm_out_kernel(
    const float* __restrict__ A, const float* __restrict__ W,
    const float* __restrict__ bias, float* __restrict__ C) {
    gemm_tile(A, W, bias, C, DM, DM);
}

// ---------------- KV stats: partial S[d,e] and z[d] per (bh, split) ----------------
// grid: (splits=16, bh=16), 256 threads. Each block handles 64 key rows.
#define JT 64
__global__ __launch_bounds__(256) void kv_stats_kernel(
    const float* __restrict__ Kbuf, const float* __restrict__ Vbuf,
    float* __restrict__ Spart, float* __restrict__ zpart) {
    const int split = blockIdx.x, bh = blockIdx.y;
    const int b = bh >> 3, h = bh & 7;
    const int j0 = split * JT;

    __shared__ float EK[JT][HD + 1];
    __shared__ float VS[JT][HD + 1];

    const int tid = threadIdx.x;
    // load 64x64 K and V chunks; 4096 floats each = 1024 float4 -> 4/thread
#pragma unroll
    for (int t = 0; t < 4; ++t) {
        int idx = tid + t * 256;     // 0..1023
        int r = idx >> 4;            // 0..63
        int c = (idx & 15) << 2;     // 0..60
        size_t row = (size_t)(b * L_ + j0 + r) * DM + h * HD + c;
        float4 kv = *(const float4*)(Kbuf + row);
        EK[r][c + 0] = __expf(kv.x); EK[r][c + 1] = __expf(kv.y);
        EK[r][c + 2] = __expf(kv.z); EK[r][c + 3] = __expf(kv.w);
        float4 vv = *(const float4*)(Vbuf + row);
        VS[r][c + 0] = vv.x; VS[r][c + 1] = vv.y;
        VS[r][c + 2] = vv.z; VS[r][c + 3] = vv.w;
    }
    __syncthreads();

    const int tx = tid & 15, ty = tid >> 4;
    float acc[4][4] = {{0.f}};
#pragma unroll 8
    for (int jj = 0; jj < JT; ++jj) {
        float ek[4], vs[4];
#pragma unroll
        for (int i = 0; i < 4; ++i) ek[i] = EK[jj][ty * 4 + i];
#pragma unroll
        for (int j = 0; j < 4; ++j) vs[j] = VS[jj][tx * 4 + j];
#pragma unroll
        for (int i = 0; i < 4; ++i)
#pragma unroll
            for (int j = 0; j < 4; ++j) acc[i][j] += ek[i] * vs[j];
    }

    float* sp = Spart + ((size_t)bh * 16 + split) * (HD * HD);
#pragma unroll
    for (int i = 0; i < 4; ++i) {
        float4 o; o.x = acc[i][0]; o.y = acc[i][1]; o.z = acc[i][2]; o.w = acc[i][3];
        *(float4*)(sp + (ty * 4 + i) * HD + tx * 4) = o;
    }
    if (tid < HD) {
        float z = 0.f;
#pragma unroll 8
        for (int jj = 0; jj < JT; ++jj) z += EK[jj][tid];
        zpart[((size_t)bh * 16 + split) * HD + tid] = z;
    }
}

// ---------------- heads: numer/denom per query row ----------------
// grid: (rowtiles=16, bh=16), 256 threads = 4 waves, 16 rows per wave.
__global__ __launch_bounds__(256) void heads_kernel(
    const float* __restrict__ Qbuf, const float* __restrict__ Spart,
    const float* __restrict__ zpart, float* __restrict__ joined) {
    const int tileI = blockIdx.x, bh = blockIdx.y;
    const int b = bh >> 3, h = bh & 7;

    __shared__ float S[HD][HD + 1];
    __shared__ float zl[HD];

    const int tid = threadIdx.x;
    // reduce 16 S partials
#pragma unroll
    for (int t = 0; t < 16; ++t) {
        int idx = tid + t * 256;         // 0..4095
        float s = 0.f;
        const float* sp = Spart + (size_t)bh * 16 * (HD * HD) + idx;
#pragma unroll
        for (int p = 0; p < 16; ++p) s += sp[(size_t)p * (HD * HD)];
        S[idx >> 6][idx & 63] = s;
    }
    if (tid < HD) {
        float z = 0.f;
        const float* zp = zpart + (size_t)bh * 16 * HD + tid;
#pragma unroll
        for (int p = 0; p < 16; ++p) z += zp[(size_t)p * HD];
        zl[tid] = z;
    }
    __syncthreads();

    const int lane = tid & 63, w = tid >> 6;
#pragma unroll 1
    for (int r = 0; r < 16; ++r) {
        int i = tileI * 64 + w * 16 + r;
        float q = Qbuf[(size_t)(b * L_ + i) * DM + h * HD + lane];
        float eq = __expf(q);

        float denom = eq * zl[lane];
#pragma unroll
        for (int off = 32; off; off >>= 1) denom += __shfl_xor(denom, off, 64);

        float acc = 0.f;
#pragma unroll
        for (int d = 0; d < HD; ++d) {
            float bq = __shfl(eq, d, 64);
            acc += bq * S[d][lane];
        }
        joined[(size_t)(b * L_ + i) * DM + h * HD + lane] = acc / denom;
    }
}

// ---------------- launch ----------------
extern "C" void kernel_launch(void* const* d_in, const int* in_sizes, int n_in,
                              void* d_out, int out_size, void* d_ws, size_t ws_size,
                              hipStream_t stream) {
    const float* x  = (const float*)d_in[0];
    const float* Wq = (const float*)d_in[1];
    const float* bq = (const float*)d_in[2];
    const float* Wk = (const float*)d_in[3];
    const float* bk = (const float*)d_in[4];
    const float* Wv = (const float*)d_in[5];
    const float* bv = (const float*)d_in[6];
    const float* Wo = (const float*)d_in[7];
    const float* bo = (const float*)d_in[8];
    float* out = (float*)d_out;

    float* ws = (float*)d_ws;
    const size_t NQ = (size_t)M_ * DM;           // 1,048,576
    float* Q      = ws;
    float* K      = ws + NQ;
    float* V      = ws + 2 * NQ;
    float* joined = ws + 3 * NQ;
    float* Spart  = ws + 4 * NQ;                  // 16*16*4096 = 1,048,576
    float* zpart  = ws + 5 * NQ;                  // 16*16*64   = 16,384

    dim3 gQKV(DM / GN, M_ / GM, 3);   // (8, 32, 3)
    gemm_qkv_kernel<<<gQKV, 256, 0, stream>>>(x, Wq, bq, Wk, bk, Wv, bv, Q, K, V);

    kv_stats_kernel<<<dim3(16, 16), 256, 0, stream>>>(K, V, Spart, zpart);

    heads_kernel<<<dim3(16, 16), 256, 0, stream>>>(Q, Spart, zpart, joined);

    dim3 gO(DM / GN, M_ / GM, 1);     // (8, 32)
    gemm_out_kernel<<<gO, 256, 0, stream>>>(joined, Wo, bo, out);
}

// Round 2
// 150.597 us; speedup vs baseline: 1.3649x; 1.3649x over previous
//
#include <hip/hip_runtime.h>
#include <math.h>

// Problem constants
#define DM   512
#define NH   8
#define HD   64
#define B_   2
#define L_   1024
#define M_   (B_ * L_)   // 2048 rows

typedef __attribute__((ext_vector_type(8))) short  bfrag;   // 8 bf16 bits (4 VGPRs)
typedef __attribute__((ext_vector_type(4))) float  fv4;     // MFMA acc
typedef __attribute__((ext_vector_type(4))) unsigned short usv4;

__device__ __forceinline__ unsigned short f32_bf16_rne(float f) {
    unsigned u = __float_as_uint(f);
    unsigned r = u + 0x7FFF + ((u >> 16) & 1);
    return (unsigned short)(r >> 16);
}
__device__ __forceinline__ float bf16_f32(unsigned short h) {
    return __uint_as_float(((unsigned)h) << 16);
}

// ---------------- split-bf16 MFMA GEMM: C = A @ W^T + bias ----------------
// A: (M, K=512) row-major fp32, W: (N=512, K=512) row-major fp32, C: (M, 512).
// C-tile 128(M) x 64(N), 256 threads = 4 waves; wave w covers rows w*32..w*32+31
// as 2x4 grid of 16x16x32 MFMA frags. A = Ah + Al split; 3 MFMA passes per frag.
#define TM 128
#define TN 64
#define TK 32
#define LDA 40   // padded LDS row stride in shorts (80 B, 16B-aligned)

__device__ __forceinline__ void mfma_gemm(const float* __restrict__ A,
                                          const float* __restrict__ W,
                                          const float* __restrict__ bias,
                                          float* __restrict__ C) {
    __shared__ __align__(16) unsigned short Ah[TM * LDA];
    __shared__ __align__(16) unsigned short Al[TM * LDA];
    __shared__ __align__(16) unsigned short Bh[TN * LDA];
    __shared__ __align__(16) unsigned short Bl[TN * LDA];

    const int tid  = threadIdx.x;
    const int wave = tid >> 6, lane = tid & 63;
    const int quad = lane >> 4, r16 = lane & 15;
    const int m0 = blockIdx.y * TM, n0 = blockIdx.x * TN;

    fv4 acc[2][4] = {};

    for (int k0 = 0; k0 < DM; k0 += TK) {
        // stage A: 128x32 fp32 -> hi/lo bf16. 1024 float4, 4 per thread.
#pragma unroll
        for (int t = 0; t < 4; ++t) {
            int idx = tid + t * 256;
            int row = idx >> 3, kc = (idx & 7) << 2;
            float4 v = *(const float4*)(A + (size_t)(m0 + row) * DM + k0 + kc);
            usv4 h, l;
            h.x = f32_bf16_rne(v.x); l.x = f32_bf16_rne(v.x - bf16_f32(h.x));
            h.y = f32_bf16_rne(v.y); l.y = f32_bf16_rne(v.y - bf16_f32(h.y));
            h.z = f32_bf16_rne(v.z); l.z = f32_bf16_rne(v.z - bf16_f32(h.z));
            h.w = f32_bf16_rne(v.w); l.w = f32_bf16_rne(v.w - bf16_f32(h.w));
            *(usv4*)(Ah + row * LDA + kc) = h;
            *(usv4*)(Al + row * LDA + kc) = l;
        }
        // stage B (rows of W): 64x32. 512 float4, 2 per thread.
#pragma unroll
        for (int t = 0; t < 2; ++t) {
            int idx = tid + t * 256;
            int row = idx >> 3, kc = (idx & 7) << 2;
            float4 v = *(const float4*)(W + (size_t)(n0 + row) * DM + k0 + kc);
            usv4 h, l;
            h.x = f32_bf16_rne(v.x); l.x = f32_bf16_rne(v.x - bf16_f32(h.x));
            h.y = f32_bf16_rne(v.y); l.y = f32_bf16_rne(v.y - bf16_f32(h.y));
            h.z = f32_bf16_rne(v.z); l.z = f32_bf16_rne(v.z - bf16_f32(h.z));
            h.w = f32_bf16_rne(v.w); l.w = f32_bf16_rne(v.w - bf16_f32(h.w));
            *(usv4*)(Bh + row * LDA + kc) = h;
            *(usv4*)(Bl + row * LDA + kc) = l;
        }
        __syncthreads();

        // fragment loads: operand elem j = T[row = idx16][k = quad*8 + j]
        bfrag ah[2], al[2], bh[4], bl[4];
#pragma unroll
        for (int i = 0; i < 2; ++i) {
            int off = (wave * 32 + i * 16 + r16) * LDA + quad * 8;
            ah[i] = *(const bfrag*)(Ah + off);
            al[i] = *(const bfrag*)(Al + off);
        }
#pragma unroll
        for (int j = 0; j < 4; ++j) {
            int off = (j * 16 + r16) * LDA + quad * 8;
            bh[j] = *(const bfrag*)(Bh + off);
            bl[j] = *(const bfrag*)(Bl + off);
        }

#pragma unroll
        for (int i = 0; i < 2; ++i)
#pragma unroll
            for (int j = 0; j < 4; ++j) {
                acc[i][j] = __builtin_amdgcn_mfma_f32_16x16x32_bf16(ah[i], bh[j], acc[i][j], 0, 0, 0);
                acc[i][j] = __builtin_amdgcn_mfma_f32_16x16x32_bf16(ah[i], bl[j], acc[i][j], 0, 0, 0);
                acc[i][j] = __builtin_amdgcn_mfma_f32_16x16x32_bf16(al[i], bh[j], acc[i][j], 0, 0, 0);
            }
        __syncthreads();
    }

    // epilogue: D[row = quad*4 + reg][col = r16] per frag
#pragma unroll
    for (int j = 0; j < 4; ++j) {
        int n = n0 + j * 16 + r16;
        float bn = bias[n];
#pragma unroll
        for (int i = 0; i < 2; ++i) {
#pragma unroll
            for (int r = 0; r < 4; ++r) {
                int m = m0 + wave * 32 + i * 16 + quad * 4 + r;
                C[(size_t)m * DM + n] = acc[i][j][r] + bn;
            }
        }
    }
}

__global__ __launch_bounds__(256) void gemm_qkv_kernel(
    const float* __restrict__ x,
    const float* __restrict__ Wq, const float* __restrict__ bq,
    const float* __restrict__ Wk, const float* __restrict__ bk,
    const float* __restrict__ Wv, const float* __restrict__ bv,
    float* __restrict__ Q, float* __restrict__ K, float* __restrict__ V) {
    const float* W; const float* b; float* C;
    if (blockIdx.z == 0)      { W = Wq; b = bq; C = Q; }
    else if (blockIdx.z == 1) { W = Wk; b = bk; C = K; }
    else                      { W = Wv; b = bv; C = V; }
    mfma_gemm(x, W, b, C);
}

__global__ __launch_bounds__(256) void gemm_out_kernel(
    const float* __restrict__ A, const float* __restrict__ W,
    const float* __restrict__ bias, float* __restrict__ C) {
    mfma_gemm(A, W, bias, C);
}

// ---------------- KV stats: partial S[d,e] and z[d] per (bh, split) ----------------
#define JT 64
__global__ __launch_bounds__(256) void kv_stats_kernel(
    const float* __restrict__ Kbuf, const float* __restrict__ Vbuf,
    float* __restrict__ Spart, float* __restrict__ zpart) {
    const int split = blockIdx.x, bh = blockIdx.y;
    const int b = bh >> 3, h = bh & 7;
    const int j0 = split * JT;

    __shared__ float EK[JT][HD + 1];
    __shared__ float VS[JT][HD + 1];

    const int tid = threadIdx.x;
#pragma unroll
    for (int t = 0; t < 4; ++t) {
        int idx = tid + t * 256;
        int r = idx >> 4;
        int c = (idx & 15) << 2;
        size_t row = (size_t)(b * L_ + j0 + r) * DM + h * HD + c;
        float4 kv = *(const float4*)(Kbuf + row);
        EK[r][c + 0] = __expf(kv.x); EK[r][c + 1] = __expf(kv.y);
        EK[r][c + 2] = __expf(kv.z); EK[r][c + 3] = __expf(kv.w);
        float4 vv = *(const float4*)(Vbuf + row);
        VS[r][c + 0] = vv.x; VS[r][c + 1] = vv.y;
        VS[r][c + 2] = vv.z; VS[r][c + 3] = vv.w;
    }
    __syncthreads();

    const int tx = tid & 15, ty = tid >> 4;
    float acc[4][4] = {{0.f}};
#pragma unroll 8
    for (int jj = 0; jj < JT; ++jj) {
        float ek[4], vs[4];
#pragma unroll
        for (int i = 0; i < 4; ++i) ek[i] = EK[jj][ty * 4 + i];
#pragma unroll
        for (int j = 0; j < 4; ++j) vs[j] = VS[jj][tx * 4 + j];
#pragma unroll
        for (int i = 0; i < 4; ++i)
#pragma unroll
            for (int j = 0; j < 4; ++j) acc[i][j] += ek[i] * vs[j];
    }

    float* sp = Spart + ((size_t)bh * 16 + split) * (HD * HD);
#pragma unroll
    for (int i = 0; i < 4; ++i) {
        float4 o; o.x = acc[i][0]; o.y = acc[i][1]; o.z = acc[i][2]; o.w = acc[i][3];
        *(float4*)(sp + (ty * 4 + i) * HD + tx * 4) = o;
    }
    if (tid < HD) {
        float z = 0.f;
#pragma unroll 8
        for (int jj = 0; jj < JT; ++jj) z += EK[jj][tid];
        zpart[((size_t)bh * 16 + split) * HD + tid] = z;
    }
}

// ---------------- heads: numer/denom per query row ----------------
__global__ __launch_bounds__(256) void heads_kernel(
    const float* __restrict__ Qbuf, const float* __restrict__ Spart,
    const float* __restrict__ zpart, float* __restrict__ joined) {
    const int tileI = blockIdx.x, bh = blockIdx.y;
    const int b = bh >> 3, h = bh & 7;

    __shared__ float S[HD][HD + 1];
    __shared__ float zl[HD];

    const int tid = threadIdx.x;
#pragma unroll
    for (int t = 0; t < 16; ++t) {
        int idx = tid + t * 256;
        float s = 0.f;
        const float* sp = Spart + (size_t)bh * 16 * (HD * HD) + idx;
#pragma unroll
        for (int p = 0; p < 16; ++p) s += sp[(size_t)p * (HD * HD)];
        S[idx >> 6][idx & 63] = s;
    }
    if (tid < HD) {
        float z = 0.f;
        const float* zp = zpart + (size_t)bh * 16 * HD + tid;
#pragma unroll
        for (int p = 0; p < 16; ++p) z += zp[(size_t)p * HD];
        zl[tid] = z;
    }
    __syncthreads();

    const int lane = tid & 63, w = tid >> 6;
#pragma unroll 1
    for (int r = 0; r < 16; ++r) {
        int i = tileI * 64 + w * 16 + r;
        float q = Qbuf[(size_t)(b * L_ + i) * DM + h * HD + lane];
        float eq = __expf(q);

        float denom = eq * zl[lane];
#pragma unroll
        for (int off = 32; off; off >>= 1) denom += __shfl_xor(denom, off, 64);

        float acc = 0.f;
#pragma unroll
        for (int d = 0; d < HD; ++d) {
            float bq = __shfl(eq, d, 64);
            acc += bq * S[d][lane];
        }
        joined[(size_t)(b * L_ + i) * DM + h * HD + lane] = acc / denom;
    }
}

// ---------------- launch ----------------
extern "C" void kernel_launch(void* const* d_in, const int* in_sizes, int n_in,
                              void* d_out, int out_size, void* d_ws, size_t ws_size,
                              hipStream_t stream) {
    const float* x  = (const float*)d_in[0];
    const float* Wq = (const float*)d_in[1];
    const float* bq = (const float*)d_in[2];
    const float* Wk = (const float*)d_in[3];
    const float* bk = (const float*)d_in[4];
    const float* Wv = (const float*)d_in[5];
    const float* bv = (const float*)d_in[6];
    const float* Wo = (const float*)d_in[7];
    const float* bo = (const float*)d_in[8];
    float* out = (float*)d_out;

    float* ws = (float*)d_ws;
    const size_t NQ = (size_t)M_ * DM;
    float* Q      = ws;
    float* K      = ws + NQ;
    float* V      = ws + 2 * NQ;
    float* joined = ws + 3 * NQ;
    float* Spart  = ws + 4 * NQ;
    float* zpart  = ws + 5 * NQ;

    dim3 gQKV(DM / TN, M_ / TM, 3);   // (8, 16, 3) = 384 blocks
    gemm_qkv_kernel<<<gQKV, 256, 0, stream>>>(x, Wq, bq, Wk, bk, Wv, bv, Q, K, V);

    kv_stats_kernel<<<dim3(16, 16), 256, 0, stream>>>(K, V, Spart, zpart);

    heads_kernel<<<dim3(16, 16), 256, 0, stream>>>(Q, Spart, zpart, joined);

    dim3 gO(DM / TN, M_ / TM, 1);     // (8, 16) = 128 blocks
    gemm_out_kernel<<<gO, 256, 0, stream>>>(joined, Wo, bo, out);
}

// Round 5
// 142.479 us; speedup vs baseline: 1.4427x; 1.0570x over previous
//
#include <hip/hip_runtime.h>
#include <math.h>

// Problem constants
#define DM   512
#define NH   8
#define HD   64
#define B_   2
#define L_   1024
#define M_   (B_ * L_)   // 2048 rows

typedef __attribute__((ext_vector_type(8))) short  bfrag;   // 8 bf16 (4 VGPRs, 16 B)
typedef __attribute__((ext_vector_type(4))) float  fv4;     // MFMA acc
typedef __attribute__((ext_vector_type(4))) unsigned short usv4;  // 8 B
typedef __attribute__((ext_vector_type(8))) unsigned short usv8;  // 16 B

__device__ __forceinline__ unsigned short f32_bf16_rne(float f) {
    unsigned u = __float_as_uint(f);
    unsigned r = u + 0x7FFF + ((u >> 16) & 1);
    return (unsigned short)(r >> 16);
}
__device__ __forceinline__ float bf16_f32(unsigned short h) {
    return __uint_as_float(((unsigned)h) << 16);
}

// ---------------- prep: fp32 -> (hi, lo) bf16 for x and all 4 weights ----------
// blocks 0..1023: x (1M floats). blocks 1024..2047: Wq,Wk,Wv,Wo (256K each).
__global__ __launch_bounds__(256) void prep_kernel(
    const float* __restrict__ x,
    const float* __restrict__ Wq, const float* __restrict__ Wk,
    const float* __restrict__ Wv, const float* __restrict__ Wo,
    unsigned short* __restrict__ xh, unsigned short* __restrict__ xl,
    unsigned short* __restrict__ wh, unsigned short* __restrict__ wl) {
    int bid = blockIdx.x;
    const float* src; unsigned short *dh, *dl; size_t off;
    if (bid < 1024) {
        src = x; dh = xh; dl = xl; off = (size_t)bid * 1024;
    } else {
        int wsel = (bid - 1024) >> 8;
        int wb   = (bid - 1024) & 255;
        src = (wsel == 0) ? Wq : (wsel == 1) ? Wk : (wsel == 2) ? Wv : Wo;
        dh = wh + (size_t)wsel * 262144;
        dl = wl + (size_t)wsel * 262144;
        off = (size_t)wb * 1024;
    }
    size_t i = off + (size_t)threadIdx.x * 4;
    float4 v = *(const float4*)(src + i);
    usv4 h, l;
    h.x = f32_bf16_rne(v.x); l.x = f32_bf16_rne(v.x - bf16_f32(h.x));
    h.y = f32_bf16_rne(v.y); l.y = f32_bf16_rne(v.y - bf16_f32(h.y));
    h.z = f32_bf16_rne(v.z); l.z = f32_bf16_rne(v.z - bf16_f32(h.z));
    h.w = f32_bf16_rne(v.w); l.w = f32_bf16_rne(v.w - bf16_f32(h.w));
    *(usv4*)(dh + i) = h;
    *(usv4*)(dl + i) = l;
}

// ---------------- split-bf16 MFMA GEMM on pre-converted inputs ----------------
// C = A @ W^T + bias (optionally exp()). A: (M,512) hi/lo bf16, W: (512,512) hi/lo.
// C-tile 128x64, 256 threads = 4 waves, 2x4 frags of 16x16x32 per wave, 3 passes.
#define TM 128
#define TN 64
#define TK 32
// LDS row stride in shorts. MUST be a multiple of 8 shorts (16 B) so the
// b128 fragment reads at row*LDA + quad*8 stay 16B-aligned (round-3 NaN #1).
#define LDA 40
// Staging chunks are 8 shorts = 16 B: MUST use usv8, not usv4 (round-3/4 NaN #2:
// usv4 stores wrote only half of each 16B chunk -> garbage in LDS).

__device__ __forceinline__ void mfma_gemm_bf16(
    const unsigned short* __restrict__ Ahg, const unsigned short* __restrict__ Alg,
    const unsigned short* __restrict__ Bhg, const unsigned short* __restrict__ Blg,
    const float* __restrict__ bias, float* __restrict__ C, int do_exp) {
    __shared__ __align__(16) unsigned short Ah[TM * LDA];
    __shared__ __align__(16) unsigned short Al[TM * LDA];
    __shared__ __align__(16) unsigned short Bh[TN * LDA];
    __shared__ __align__(16) unsigned short Bl[TN * LDA];

    const int tid  = threadIdx.x;
    const int wave = tid >> 6, lane = tid & 63;
    const int quad = lane >> 4, r16 = lane & 15;
    const int m0 = blockIdx.y * TM, n0 = blockIdx.x * TN;

    fv4 acc[2][4] = {};

    for (int k0 = 0; k0 < DM; k0 += TK) {
        // A: 128 rows x 4 chunks(8 shorts, 16 B) = 512 chunks -> 2/thread (hi & lo)
#pragma unroll
        for (int t = 0; t < 2; ++t) {
            int idx = tid + t * 256;
            int row = idx >> 2, ch = (idx & 3) << 3;          // ch in shorts
            size_t g = (size_t)(m0 + row) * DM + k0 + ch;
            *(usv8*)(Ah + row * LDA + ch) = *(const usv8*)(Ahg + g);
            *(usv8*)(Al + row * LDA + ch) = *(const usv8*)(Alg + g);
        }
        // B: 64 rows x 4 chunks = 256 chunks -> 1/thread (hi & lo)
        {
            int row = tid >> 2, ch = (tid & 3) << 3;
            size_t g = (size_t)(n0 + row) * DM + k0 + ch;
            *(usv8*)(Bh + row * LDA + ch) = *(const usv8*)(Bhg + g);
            *(usv8*)(Bl + row * LDA + ch) = *(const usv8*)(Blg + g);
        }
        __syncthreads();

        bfrag ah[2], al[2], bh[4], bl[4];
#pragma unroll
        for (int i = 0; i < 2; ++i) {
            int off = (wave * 32 + i * 16 + r16) * LDA + quad * 8;
            ah[i] = *(const bfrag*)(Ah + off);
            al[i] = *(const bfrag*)(Al + off);
        }
#pragma unroll
        for (int j = 0; j < 4; ++j) {
            int off = (j * 16 + r16) * LDA + quad * 8;
            bh[j] = *(const bfrag*)(Bh + off);
            bl[j] = *(const bfrag*)(Bl + off);
        }

#pragma unroll
        for (int i = 0; i < 2; ++i)
#pragma unroll
            for (int j = 0; j < 4; ++j) {
                acc[i][j] = __builtin_amdgcn_mfma_f32_16x16x32_bf16(ah[i], bh[j], acc[i][j], 0, 0, 0);
                acc[i][j] = __builtin_amdgcn_mfma_f32_16x16x32_bf16(ah[i], bl[j], acc[i][j], 0, 0, 0);
                acc[i][j] = __builtin_amdgcn_mfma_f32_16x16x32_bf16(al[i], bh[j], acc[i][j], 0, 0, 0);
            }
        __syncthreads();
    }

    // epilogue: D[row = quad*4 + r][col = r16]
#pragma unroll
    for (int j = 0; j < 4; ++j) {
        int n = n0 + j * 16 + r16;
        float bn = bias[n];
#pragma unroll
        for (int i = 0; i < 2; ++i) {
#pragma unroll
            for (int r = 0; r < 4; ++r) {
                int m = m0 + wave * 32 + i * 16 + quad * 4 + r;
                float v = acc[i][j][r] + bn;
                if (do_exp) v = __expf(v);
                C[(size_t)m * DM + n] = v;
            }
        }
    }
}

// QKV: z=0 -> exp(Q), z=1 -> exp(K), z=2 -> V
__global__ __launch_bounds__(256) void gemm_qkv_kernel(
    const unsigned short* __restrict__ xh, const unsigned short* __restrict__ xl,
    const unsigned short* __restrict__ wh, const unsigned short* __restrict__ wl,
    const float* __restrict__ bq, const float* __restrict__ bk, const float* __restrict__ bv,
    float* __restrict__ Qe, float* __restrict__ Ke, float* __restrict__ V) {
    int z = blockIdx.z;
    const float* b = (z == 0) ? bq : (z == 1) ? bk : bv;
    float* C = (z == 0) ? Qe : (z == 1) ? Ke : V;
    mfma_gemm_bf16(xh, xl, wh + (size_t)z * 262144, wl + (size_t)z * 262144,
                   b, C, z < 2);
}

__global__ __launch_bounds__(256) void gemm_out_kernel(
    const unsigned short* __restrict__ jh, const unsigned short* __restrict__ jl,
    const unsigned short* __restrict__ wh, const unsigned short* __restrict__ wl,
    const float* __restrict__ bo, float* __restrict__ C) {
    mfma_gemm_bf16(jh, jl, wh + (size_t)3 * 262144, wl + (size_t)3 * 262144,
                   bo, C, 0);
}

// ---------------- KV stats: partial S[d,e] and z[d] per (bh, split) ----------------
// Kbuf already holds exp(K).
#define JT 64
__global__ __launch_bounds__(256) void kv_stats_kernel(
    const float* __restrict__ Kbuf, const float* __restrict__ Vbuf,
    float* __restrict__ Spart, float* __restrict__ zpart) {
    const int split = blockIdx.x, bh = blockIdx.y;
    const int b = bh >> 3, h = bh & 7;
    const int j0 = split * JT;

    __shared__ float EK[JT][HD + 1];
    __shared__ float VS[JT][HD + 1];

    const int tid = threadIdx.x;
#pragma unroll
    for (int t = 0; t < 4; ++t) {
        int idx = tid + t * 256;
        int r = idx >> 4;
        int c = (idx & 15) << 2;
        size_t row = (size_t)(b * L_ + j0 + r) * DM + h * HD + c;
        float4 kv = *(const float4*)(Kbuf + row);
        EK[r][c + 0] = kv.x; EK[r][c + 1] = kv.y;
        EK[r][c + 2] = kv.z; EK[r][c + 3] = kv.w;
        float4 vv = *(const float4*)(Vbuf + row);
        VS[r][c + 0] = vv.x; VS[r][c + 1] = vv.y;
        VS[r][c + 2] = vv.z; VS[r][c + 3] = vv.w;
    }
    __syncthreads();

    const int tx = tid & 15, ty = tid >> 4;
    float acc[4][4] = {{0.f}};
#pragma unroll 8
    for (int jj = 0; jj < JT; ++jj) {
        float ek[4], vs[4];
#pragma unroll
        for (int i = 0; i < 4; ++i) ek[i] = EK[jj][ty * 4 + i];
#pragma unroll
        for (int j = 0; j < 4; ++j) vs[j] = VS[jj][tx * 4 + j];
#pragma unroll
        for (int i = 0; i < 4; ++i)
#pragma unroll
            for (int j = 0; j < 4; ++j) acc[i][j] += ek[i] * vs[j];
    }

    float* sp = Spart + ((size_t)bh * 16 + split) * (HD * HD);
#pragma unroll
    for (int i = 0; i < 4; ++i) {
        float4 o; o.x = acc[i][0]; o.y = acc[i][1]; o.z = acc[i][2]; o.w = acc[i][3];
        *(float4*)(sp + (ty * 4 + i) * HD + tx * 4) = o;
    }
    if (tid < HD) {
        float z = 0.f;
#pragma unroll 8
        for (int jj = 0; jj < JT; ++jj) z += EK[jj][tid];
        zpart[((size_t)bh * 16 + split) * HD + tid] = z;
    }
}

// ---------------- heads: numer/denom per query row; writes joined as hi/lo bf16 ----
// Qbuf already holds exp(Q).
__global__ __launch_bounds__(256) void heads_kernel(
    const float* __restrict__ Qbuf, const float* __restrict__ Spart,
    const float* __restrict__ zpart,
    unsigned short* __restrict__ jh, unsigned short* __restrict__ jl) {
    const int tileI = blockIdx.x, bh = blockIdx.y;
    const int b = bh >> 3, h = bh & 7;

    __shared__ float S[HD][HD + 1];
    __shared__ float zl[HD];

    const int tid = threadIdx.x;
#pragma unroll
    for (int t = 0; t < 16; ++t) {
        int idx = tid + t * 256;
        float s = 0.f;
        const float* sp = Spart + (size_t)bh * 16 * (HD * HD) + idx;
#pragma unroll
        for (int p = 0; p < 16; ++p) s += sp[(size_t)p * (HD * HD)];
        S[idx >> 6][idx & 63] = s;
    }
    if (tid < HD) {
        float z = 0.f;
        const float* zp = zpart + (size_t)bh * 16 * HD + tid;
#pragma unroll
        for (int p = 0; p < 16; ++p) z += zp[(size_t)p * HD];
        zl[tid] = z;
    }
    __syncthreads();

    const int lane = tid & 63, w = tid >> 6;
#pragma unroll 1
    for (int r = 0; r < 16; ++r) {
        int i = tileI * 64 + w * 16 + r;
        float eq = Qbuf[(size_t)(b * L_ + i) * DM + h * HD + lane];

        float denom = eq * zl[lane];
#pragma unroll
        for (int off = 32; off; off >>= 1) denom += __shfl_xor(denom, off, 64);

        float acc = 0.f;
#pragma unroll
        for (int d = 0; d < HD; ++d) {
            float bq = __shfl(eq, d, 64);
            acc += bq * S[d][lane];
        }
        float val = acc / denom;
        size_t oidx = (size_t)(b * L_ + i) * DM + h * HD + lane;
        unsigned short hh = f32_bf16_rne(val);
        unsigned short ll = f32_bf16_rne(val - bf16_f32(hh));
        jh[oidx] = hh;
        jl[oidx] = ll;
    }
}

// ---------------- launch ----------------
extern "C" void kernel_launch(void* const* d_in, const int* in_sizes, int n_in,
                              void* d_out, int out_size, void* d_ws, size_t ws_size,
                              hipStream_t stream) {
    const float* x  = (const float*)d_in[0];
    const float* Wq = (const float*)d_in[1];
    const float* bq = (const float*)d_in[2];
    const float* Wk = (const float*)d_in[3];
    const float* bk = (const float*)d_in[4];
    const float* Wv = (const float*)d_in[5];
    const float* bv = (const float*)d_in[6];
    const float* Wo = (const float*)d_in[7];
    const float* bo = (const float*)d_in[8];
    float* out = (float*)d_out;

    float* f = (float*)d_ws;
    const size_t NQ = (size_t)M_ * DM;               // 1,048,576
    float* Qe    = f;
    float* Ke    = f + NQ;
    float* V     = f + 2 * NQ;
    float* Spart = f + 3 * NQ;                        // 16*16*4096 = 1M floats
    float* zpart = f + 4 * NQ;                        // 16K floats
    unsigned short* u = (unsigned short*)(f + 4 * NQ + 16384);
    unsigned short* xh = u;
    unsigned short* xl = u + NQ;
    unsigned short* wh = u + 2 * NQ;                  // 4 x 262144
    unsigned short* wl = u + 3 * NQ;
    unsigned short* jh = u + 4 * NQ;
    unsigned short* jl = u + 5 * NQ;

    prep_kernel<<<2048, 256, 0, stream>>>(x, Wq, Wk, Wv, Wo, xh, xl, wh, wl);

    dim3 gQKV(DM / TN, M_ / TM, 3);   // (8, 16, 3)
    gemm_qkv_kernel<<<gQKV, 256, 0, stream>>>(xh, xl, wh, wl, bq, bk, bv, Qe, Ke, V);

    kv_stats_kernel<<<dim3(16, 16), 256, 0, stream>>>(Ke, V, Spart, zpart);

    heads_kernel<<<dim3(16, 16), 256, 0, stream>>>(Qe, Spart, zpart, jh, jl);

    dim3 gO(DM / TN, M_ / TM, 1);     // (8, 16)
    gemm_out_kernel<<<gO, 256, 0, stream>>>(jh, jl, wh, wl, bo, out);
}